// Round 1
// baseline (468.980 us; speedup 1.0000x reference)
//
#include <hip/hip_runtime.h>

#define D 64

// ---------------- CSR build ----------------

__global__ void hist_kernel(const int* __restrict__ dst, int E, int N,
                            int* __restrict__ deg) {
    int e = blockIdx.x * blockDim.x + threadIdx.x;
    int total = E + N;
    if (e >= total) return;
    int d = (e < E) ? dst[e] : (e - E);
    atomicAdd(&deg[d], 1);
}

__global__ void scan1_kernel(const int* __restrict__ deg, int* __restrict__ rowptr,
                             int* __restrict__ bsum, int N) {
    __shared__ int tmp[256];
    int t = threadIdx.x;
    int idx = blockIdx.x * 256 + t;
    int v = (idx < N) ? deg[idx] : 0;
    tmp[t] = v;
    __syncthreads();
    for (int off = 1; off < 256; off <<= 1) {
        int add = (t >= off) ? tmp[t - off] : 0;
        __syncthreads();
        tmp[t] += add;
        __syncthreads();
    }
    if (idx < N) rowptr[idx] = tmp[t] - v;           // block-local exclusive
    if (t == 255) bsum[blockIdx.x] = tmp[255];       // block total
}

__global__ void scan2_kernel(int* __restrict__ bsum, int nb) {
    __shared__ int tmp[256];
    int t = threadIdx.x;
    int v = (t < nb) ? bsum[t] : 0;
    tmp[t] = v;
    __syncthreads();
    for (int off = 1; off < 256; off <<= 1) {
        int add = (t >= off) ? tmp[t - off] : 0;
        __syncthreads();
        tmp[t] += add;
        __syncthreads();
    }
    if (t < nb) bsum[t] = tmp[t] - v;                // exclusive block offsets
}

__global__ void scan3_kernel(int* __restrict__ rowptr, const int* __restrict__ bsum,
                             int* __restrict__ cursor, int N) {
    int idx = blockIdx.x * 256 + threadIdx.x;
    if (idx >= N) return;
    int v = rowptr[idx] + bsum[blockIdx.x];
    rowptr[idx] = v;
    cursor[idx] = v;
}

__global__ void scatter_kernel(const int* __restrict__ edges, int E, int N,
                               int* __restrict__ cursor, int* __restrict__ csr_src) {
    int e = blockIdx.x * blockDim.x + threadIdx.x;
    int total = E + N;
    if (e >= total) return;
    int s, d;
    if (e < E) { s = edges[e]; d = edges[E + e]; }
    else       { s = d = e - E; }
    int pos = atomicAdd(&cursor[d], 1);
    csr_src[pos] = s;
}

// ---------------- h = x @ W, plus per-node attention scalars ----------------
// One wave per node: lane d owns h[i][d]. W staged in LDS (16 KB).

__global__ __launch_bounds__(256) void gemm_attn_kernel(
    const float* __restrict__ x, const float* __restrict__ W,
    const float* __restrict__ a_src, const float* __restrict__ a_dst,
    float* __restrict__ h, float* __restrict__ hs, float* __restrict__ hd, int N)
{
    __shared__ float Wl[D * D];
    int t = threadIdx.x;
    for (int k = t; k < D * D; k += 256) Wl[k] = W[k];
    __syncthreads();

    int wave = t >> 6;
    int lane = t & 63;
    int i = blockIdx.x * 4 + wave;
    if (i >= N) return;

    float xv = x[(size_t)i * D + lane];
    float acc = 0.f;
    #pragma unroll
    for (int k = 0; k < D; ++k)
        acc += __shfl(xv, k) * Wl[k * D + lane];

    h[(size_t)i * D + lane] = acc;

    float vs = acc * a_src[lane];
    float vd = acc * a_dst[lane];
    #pragma unroll
    for (int off = 32; off > 0; off >>= 1) {
        vs += __shfl_xor(vs, off);
        vd += __shfl_xor(vd, off);
    }
    if (lane == 0) { hs[i] = vs; hd[i] = vd; }
}

// ---------------- segment softmax + aggregation (one wave per dst node) -----

template <bool RELU>
__global__ __launch_bounds__(256) void gather_kernel(
    const float* __restrict__ h, const float* __restrict__ hs,
    const float* __restrict__ hd,
    const int* __restrict__ rowptr, const int* __restrict__ deg,
    const int* __restrict__ csr_src,
    const float* __restrict__ bias, float* __restrict__ out, int N)
{
    int t = threadIdx.x;
    int wave = t >> 6;
    int lane = t & 63;
    int i = blockIdx.x * 4 + wave;
    if (i >= N) return;

    int start = rowptr[i];
    int cnt = deg[i];
    float hdv = hd[i];

    // pass 1: max logit (scalar reads only)
    float m = -1e30f;
    for (int k = 0; k < cnt; ++k) {
        int j = csr_src[start + k];
        float l = hs[j] + hdv;
        l = (l > 0.f) ? l : 0.2f * l;
        m = fmaxf(m, l);
    }

    // pass 2: exp, sum, weighted feature accumulation
    float s = 0.f, o = 0.f;
    for (int k = 0; k < cnt; ++k) {
        int j = csr_src[start + k];
        float l = hs[j] + hdv;
        l = (l > 0.f) ? l : 0.2f * l;
        float p = __expf(l - m);
        s += p;
        o += p * h[(size_t)j * D + lane];
    }

    float r = o / s + bias[lane];
    if (RELU) r = fmaxf(r, 0.f);
    out[(size_t)i * D + lane] = r;
}

// ---------------- launch ----------------

extern "C" void kernel_launch(void* const* d_in, const int* in_sizes, int n_in,
                              void* d_out, int out_size, void* d_ws, size_t ws_size,
                              hipStream_t stream)
{
    const float* embeds = (const float*)d_in[0];
    const int*   edges  = (const int*)d_in[1];   // [2, E] row-major
    const float* W1  = (const float*)d_in[2];
    const float* as1 = (const float*)d_in[3];
    const float* ad1 = (const float*)d_in[4];
    const float* b1  = (const float*)d_in[5];
    const float* W2  = (const float*)d_in[6];
    const float* as2 = (const float*)d_in[7];
    const float* ad2 = (const float*)d_in[8];
    const float* b2  = (const float*)d_in[9];

    int N = in_sizes[0] / D;
    int E = in_sizes[1] / 2;
    int total = E + N;

    char* ws = (char*)d_ws;
    float* h   = (float*)ws;  ws += (size_t)N * D * 4;
    float* x1  = (float*)ws;  ws += (size_t)N * D * 4;
    float* hs  = (float*)ws;  ws += (size_t)N * 4;
    float* hd  = (float*)ws;  ws += (size_t)N * 4;
    int* deg     = (int*)ws;  ws += (size_t)N * 4;
    int* rowptr  = (int*)ws;  ws += (size_t)N * 4;
    int* cursor  = (int*)ws;  ws += (size_t)N * 4;
    int* bsum    = (int*)ws;  ws += 1024 * 4;
    int* csr_src = (int*)ws;  ws += (size_t)total * 4;

    hipMemsetAsync(deg, 0, (size_t)N * 4, stream);

    const int tb = 256;
    int nbE = (total + tb - 1) / tb;
    int nbS = (N + tb - 1) / tb;      // 196 for N=50000 (fits scan2's 256)
    int nbN = (N + 3) / 4;

    hist_kernel<<<nbE, tb, 0, stream>>>(edges + E, E, N, deg);
    scan1_kernel<<<nbS, tb, 0, stream>>>(deg, rowptr, bsum, N);
    scan2_kernel<<<1, tb, 0, stream>>>(bsum, nbS);
    scan3_kernel<<<nbS, tb, 0, stream>>>(rowptr, bsum, cursor, N);
    scatter_kernel<<<nbE, tb, 0, stream>>>(edges, E, N, cursor, csr_src);

    // layer 1
    gemm_attn_kernel<<<nbN, 256, 0, stream>>>(embeds, W1, as1, ad1, h, hs, hd, N);
    gather_kernel<true><<<nbN, 256, 0, stream>>>(h, hs, hd, rowptr, deg, csr_src,
                                                 b1, x1, N);
    // layer 2
    gemm_attn_kernel<<<nbN, 256, 0, stream>>>(x1, W2, as2, ad2, h, hs, hd, N);
    gather_kernel<false><<<nbN, 256, 0, stream>>>(h, hs, hd, rowptr, deg, csr_src,
                                                  b2, (float*)d_out, N);
}

// Round 2
// 293.587 us; speedup vs baseline: 1.5974x; 1.5974x over previous
//
#include <hip/hip_runtime.h>

#define D 64

// ---------------- CSR build ----------------

__global__ void hist_kernel(const int* __restrict__ dst, int E, int N,
                            int* __restrict__ deg) {
    int e = blockIdx.x * blockDim.x + threadIdx.x;
    int total = E + N;
    if (e >= total) return;
    int d = (e < E) ? dst[e] : (e - E);
    atomicAdd(&deg[d], 1);
}

__global__ void scan1_kernel(const int* __restrict__ deg, int* __restrict__ rowptr,
                             int* __restrict__ bsum, int N) {
    __shared__ int tmp[256];
    int t = threadIdx.x;
    int idx = blockIdx.x * 256 + t;
    int v = (idx < N) ? deg[idx] : 0;
    tmp[t] = v;
    __syncthreads();
    for (int off = 1; off < 256; off <<= 1) {
        int add = (t >= off) ? tmp[t - off] : 0;
        __syncthreads();
        tmp[t] += add;
        __syncthreads();
    }
    if (idx < N) rowptr[idx] = tmp[t] - v;           // block-local exclusive
    if (t == 255) bsum[blockIdx.x] = tmp[255];       // block total
}

__global__ void scan2_kernel(int* __restrict__ bsum, int nb) {
    __shared__ int tmp[256];
    int t = threadIdx.x;
    int v = (t < nb) ? bsum[t] : 0;
    tmp[t] = v;
    __syncthreads();
    for (int off = 1; off < 256; off <<= 1) {
        int add = (t >= off) ? tmp[t - off] : 0;
        __syncthreads();
        tmp[t] += add;
        __syncthreads();
    }
    if (t < nb) bsum[t] = tmp[t] - v;                // exclusive block offsets
}

__global__ void scan3_kernel(int* __restrict__ rowptr, const int* __restrict__ bsum,
                             int* __restrict__ cursor, int N) {
    int idx = blockIdx.x * 256 + threadIdx.x;
    if (idx >= N) return;
    int v = rowptr[idx] + bsum[blockIdx.x];
    rowptr[idx] = v;
    cursor[idx] = v;
}

__global__ void scatter_kernel(const int* __restrict__ edges, int E, int N,
                               int* __restrict__ cursor, int* __restrict__ csr_src) {
    int e = blockIdx.x * blockDim.x + threadIdx.x;
    int total = E + N;
    if (e >= total) return;
    int s, d;
    if (e < E) { s = edges[e]; d = edges[E + e]; }
    else       { s = d = e - E; }
    int pos = atomicAdd(&cursor[d], 1);
    csr_src[pos] = s;
}

// ---------------- h = x @ W, plus per-node attention scalars ----------------

__global__ __launch_bounds__(256) void gemm_attn_kernel(
    const float* __restrict__ x, const float* __restrict__ W,
    const float* __restrict__ a_src, const float* __restrict__ a_dst,
    float* __restrict__ h, float* __restrict__ hs, float* __restrict__ hd, int N)
{
    __shared__ float Wl[D * D];
    int t = threadIdx.x;
    for (int k = t; k < D * D; k += 256) Wl[k] = W[k];
    __syncthreads();

    int wave = t >> 6;
    int lane = t & 63;
    int i = blockIdx.x * 4 + wave;
    if (i >= N) return;

    float xv = x[(size_t)i * D + lane];
    float acc = 0.f;
    #pragma unroll
    for (int k = 0; k < D; ++k)
        acc += __shfl(xv, k) * Wl[k * D + lane];

    h[(size_t)i * D + lane] = acc;

    float vs = acc * a_src[lane];
    float vd = acc * a_dst[lane];
    #pragma unroll
    for (int off = 32; off > 0; off >>= 1) {
        vs += __shfl_xor(vs, off);
        vd += __shfl_xor(vd, off);
    }
    if (lane == 0) { hs[i] = vs; hd[i] = vd; }
}

// ---------------- segment softmax + aggregation (one wave per dst node) -----
// Lane-parallel over edges: lanes 0..63 each own one incoming edge of node i
// (chunked by 64 with exact online rescale; ~all nodes have degree <= 64).

__device__ __forceinline__ float rl_f(float v, int l) {
    return __uint_as_float(__builtin_amdgcn_readlane(__float_as_uint(v), l));
}

template <bool RELU>
__global__ __launch_bounds__(256) void gather_kernel(
    const float* __restrict__ h, const float* __restrict__ hs,
    const float* __restrict__ hd,
    const int* __restrict__ rowptr, const int* __restrict__ deg,
    const int* __restrict__ csr_src,
    const float* __restrict__ bias, float* __restrict__ out, int N)
{
    int t = threadIdx.x;
    int wave = t >> 6;
    int lane = t & 63;
    int i = blockIdx.x * 4 + wave;
    if (i >= N) return;

    int start = rowptr[i];
    int cnt = deg[i];
    float hdv = hd[i];

    float m = -1e30f, s = 0.f, o = 0.f;

    for (int base = 0; base < cnt; base += 64) {
        int rem = cnt - base; if (rem > 64) rem = 64;

        int myj = 0; float myl = -1e30f;
        if (lane < rem) {
            myj = csr_src[start + base + lane];
            float l = hs[myj] + hdv;
            myl = (l > 0.f) ? l : 0.2f * l;
        }

        // wave max of this chunk
        float cm = myl;
        #pragma unroll
        for (int off = 32; off; off >>= 1) cm = fmaxf(cm, __shfl_xor(cm, off));
        if (cm > m) {                       // wave-uniform rescale (exact)
            float sc = __expf(m - cm);
            s *= sc; o *= sc; m = cm;
        }

        float p = __expf(myl - m);          // lanes >= rem: exp(-1e30) == 0
        float cs = p;
        #pragma unroll
        for (int off = 32; off; off >>= 1) cs += __shfl_xor(cs, off);
        s += cs;

        // weighted accumulation: broadcast (j, p) per edge, gather h row
        int e = 0;
        for (; e + 4 <= rem; e += 4) {
            int j0 = __builtin_amdgcn_readlane(myj, e);
            int j1 = __builtin_amdgcn_readlane(myj, e + 1);
            int j2 = __builtin_amdgcn_readlane(myj, e + 2);
            int j3 = __builtin_amdgcn_readlane(myj, e + 3);
            float p0 = rl_f(p, e),     p1 = rl_f(p, e + 1);
            float p2 = rl_f(p, e + 2), p3 = rl_f(p, e + 3);
            float v0 = h[(size_t)j0 * D + lane];
            float v1 = h[(size_t)j1 * D + lane];
            float v2 = h[(size_t)j2 * D + lane];
            float v3 = h[(size_t)j3 * D + lane];
            o += p0 * v0; o += p1 * v1; o += p2 * v2; o += p3 * v3;
        }
        for (; e < rem; ++e) {
            int j0 = __builtin_amdgcn_readlane(myj, e);
            float p0 = rl_f(p, e);
            o += p0 * h[(size_t)j0 * D + lane];
        }
    }

    float r = o / s + bias[lane];
    if (RELU) r = fmaxf(r, 0.f);
    out[(size_t)i * D + lane] = r;
}

// ---------------- launch ----------------

extern "C" void kernel_launch(void* const* d_in, const int* in_sizes, int n_in,
                              void* d_out, int out_size, void* d_ws, size_t ws_size,
                              hipStream_t stream)
{
    const float* embeds = (const float*)d_in[0];
    const int*   edges  = (const int*)d_in[1];   // [2, E] row-major
    const float* W1  = (const float*)d_in[2];
    const float* as1 = (const float*)d_in[3];
    const float* ad1 = (const float*)d_in[4];
    const float* b1  = (const float*)d_in[5];
    const float* W2  = (const float*)d_in[6];
    const float* as2 = (const float*)d_in[7];
    const float* ad2 = (const float*)d_in[8];
    const float* b2  = (const float*)d_in[9];

    int N = in_sizes[0] / D;
    int E = in_sizes[1] / 2;
    int total = E + N;

    char* ws = (char*)d_ws;
    float* h   = (float*)ws;  ws += (size_t)N * D * 4;
    float* x1  = (float*)ws;  ws += (size_t)N * D * 4;
    float* hs  = (float*)ws;  ws += (size_t)N * 4;
    float* hd  = (float*)ws;  ws += (size_t)N * 4;
    int* deg     = (int*)ws;  ws += (size_t)N * 4;
    int* rowptr  = (int*)ws;  ws += (size_t)N * 4;
    int* cursor  = (int*)ws;  ws += (size_t)N * 4;
    int* bsum    = (int*)ws;  ws += 1024 * 4;
    int* csr_src = (int*)ws;  ws += (size_t)total * 4;

    hipMemsetAsync(deg, 0, (size_t)N * 4, stream);

    const int tb = 256;
    int nbE = (total + tb - 1) / tb;
    int nbS = (N + tb - 1) / tb;      // 196 for N=50000 (fits scan2's 256)
    int nbN = (N + 3) / 4;

    hist_kernel<<<nbE, tb, 0, stream>>>(edges + E, E, N, deg);
    scan1_kernel<<<nbS, tb, 0, stream>>>(deg, rowptr, bsum, N);
    scan2_kernel<<<1, tb, 0, stream>>>(bsum, nbS);
    scan3_kernel<<<nbS, tb, 0, stream>>>(rowptr, bsum, cursor, N);
    scatter_kernel<<<nbE, tb, 0, stream>>>(edges, E, N, cursor, csr_src);

    // layer 1
    gemm_attn_kernel<<<nbN, 256, 0, stream>>>(embeds, W1, as1, ad1, h, hs, hd, N);
    gather_kernel<true><<<nbN, 256, 0, stream>>>(h, hs, hd, rowptr, deg, csr_src,
                                                 b1, x1, N);
    // layer 2
    gemm_attn_kernel<<<nbN, 256, 0, stream>>>(x1, W2, as2, ad2, h, hs, hd, N);
    gather_kernel<false><<<nbN, 256, 0, stream>>>(h, hs, hd, rowptr, deg, csr_src,
                                                  b2, (float*)d_out, N);
}

// Round 3
// 252.165 us; speedup vs baseline: 1.8598x; 1.1643x over previous
//
#include <hip/hip_runtime.h>

#define D 64

// ---------------- CSR build ----------------

__global__ void hist_kernel(const int* __restrict__ dst, int E, int N,
                            int* __restrict__ deg) {
    int e = blockIdx.x * blockDim.x + threadIdx.x;
    int total = E + N;
    if (e >= total) return;
    int d = (e < E) ? dst[e] : (e - E);
    atomicAdd(&deg[d], 1);
}

__global__ void scan1_kernel(const int* __restrict__ deg, int* __restrict__ rowptr,
                             int* __restrict__ bsum, int N) {
    __shared__ int tmp[256];
    int t = threadIdx.x;
    int idx = blockIdx.x * 256 + t;
    int v = (idx < N) ? deg[idx] : 0;
    tmp[t] = v;
    __syncthreads();
    for (int off = 1; off < 256; off <<= 1) {
        int add = (t >= off) ? tmp[t - off] : 0;
        __syncthreads();
        tmp[t] += add;
        __syncthreads();
    }
    if (idx < N) rowptr[idx] = tmp[t] - v;           // block-local exclusive
    if (t == 255) bsum[blockIdx.x] = tmp[255];       // block total
}

__global__ void scan2_kernel(int* __restrict__ bsum, int nb) {
    __shared__ int tmp[256];
    int t = threadIdx.x;
    int v = (t < nb) ? bsum[t] : 0;
    tmp[t] = v;
    __syncthreads();
    for (int off = 1; off < 256; off <<= 1) {
        int add = (t >= off) ? tmp[t - off] : 0;
        __syncthreads();
        tmp[t] += add;
        __syncthreads();
    }
    if (t < nb) bsum[t] = tmp[t] - v;                // exclusive block offsets
}

__global__ void scan3_kernel(int* __restrict__ rowptr, const int* __restrict__ bsum,
                             int* __restrict__ cursor, int N) {
    int idx = blockIdx.x * 256 + threadIdx.x;
    if (idx >= N) return;
    int v = rowptr[idx] + bsum[blockIdx.x];
    rowptr[idx] = v;
    cursor[idx] = v;
}

__global__ void scatter_kernel(const int* __restrict__ edges, int E, int N,
                               int* __restrict__ cursor, int* __restrict__ csr_src) {
    int e = blockIdx.x * blockDim.x + threadIdx.x;
    int total = E + N;
    if (e >= total) return;
    int s, d;
    if (e < E) { s = edges[e]; d = edges[E + e]; }
    else       { s = d = e - E; }
    int pos = atomicAdd(&cursor[d], 1);
    csr_src[pos] = s;
}

// ---------------- h = x @ W, plus per-node attention scalars ----------------
// Lane holds W column `lane` in 64 VGPRs (compile-time indexed). x-row read
// with uniform-address float4 loads (1 cacheline fetch, broadcast to lanes).
// No LDS, no shfl in the inner loop. 16 nodes per wave amortize the W load.

#define NODES_PER_WAVE 16

__global__ __launch_bounds__(256) void gemm_attn_kernel(
    const float* __restrict__ x, const float* __restrict__ W,
    const float* __restrict__ a_src, const float* __restrict__ a_dst,
    float* __restrict__ h, float* __restrict__ hs, float* __restrict__ hd, int N)
{
    int t = threadIdx.x;
    int wave = t >> 6;
    int lane = t & 63;

    float Wc[D];
    #pragma unroll
    for (int k = 0; k < D; ++k) Wc[k] = W[k * D + lane];   // coalesced per k
    float asv = a_src[lane], adv = a_dst[lane];

    int node0 = (blockIdx.x * 4 + wave) * NODES_PER_WAVE;
    for (int n = 0; n < NODES_PER_WAVE; ++n) {
        int i = node0 + n;
        if (i >= N) break;                 // wave-uniform

        const float4* xr = (const float4*)(x + (size_t)i * D);
        float a0 = 0.f, a1 = 0.f, a2 = 0.f, a3 = 0.f;
        #pragma unroll
        for (int kk = 0; kk < D / 4; ++kk) {
            float4 xv = xr[kk];            // uniform-address broadcast load
            a0 = fmaf(xv.x, Wc[4 * kk + 0], a0);
            a1 = fmaf(xv.y, Wc[4 * kk + 1], a1);
            a2 = fmaf(xv.z, Wc[4 * kk + 2], a2);
            a3 = fmaf(xv.w, Wc[4 * kk + 3], a3);
        }
        float acc = (a0 + a1) + (a2 + a3);

        h[(size_t)i * D + lane] = acc;

        float vs = acc * asv;
        float vd = acc * adv;
        #pragma unroll
        for (int off = 32; off > 0; off >>= 1) {
            vs += __shfl_xor(vs, off);
            vd += __shfl_xor(vd, off);
        }
        if (lane == 0) { hs[i] = vs; hd[i] = vd; }
    }
}

// ---------------- segment softmax + aggregation (one wave per dst node) -----
// Lane-parallel over edges: lanes 0..63 each own one incoming edge of node i
// (chunked by 64 with exact online rescale; ~all nodes have degree <= 64).

__device__ __forceinline__ float rl_f(float v, int l) {
    return __uint_as_float(__builtin_amdgcn_readlane(__float_as_uint(v), l));
}

template <bool RELU>
__global__ __launch_bounds__(256) void gather_kernel(
    const float* __restrict__ h, const float* __restrict__ hs,
    const float* __restrict__ hd,
    const int* __restrict__ rowptr, const int* __restrict__ deg,
    const int* __restrict__ csr_src,
    const float* __restrict__ bias, float* __restrict__ out, int N)
{
    int t = threadIdx.x;
    int wave = t >> 6;
    int lane = t & 63;
    int i = blockIdx.x * 4 + wave;
    if (i >= N) return;

    int start = rowptr[i];
    int cnt = deg[i];
    float hdv = hd[i];

    float m = -1e30f, s = 0.f, o = 0.f;

    for (int base = 0; base < cnt; base += 64) {
        int rem = cnt - base; if (rem > 64) rem = 64;

        int myj = 0; float myl = -1e30f;
        if (lane < rem) {
            myj = csr_src[start + base + lane];
            float l = hs[myj] + hdv;
            myl = (l > 0.f) ? l : 0.2f * l;
        }

        // wave max of this chunk
        float cm = myl;
        #pragma unroll
        for (int off = 32; off; off >>= 1) cm = fmaxf(cm, __shfl_xor(cm, off));
        if (cm > m) {                       // wave-uniform rescale (exact)
            float sc = __expf(m - cm);
            s *= sc; o *= sc; m = cm;
        }

        float p = __expf(myl - m);          // lanes >= rem: exp(-1e30) == 0
        float cs = p;
        #pragma unroll
        for (int off = 32; off; off >>= 1) cs += __shfl_xor(cs, off);
        s += cs;

        // weighted accumulation: broadcast (j, p) per edge, gather h row
        int e = 0;
        for (; e + 4 <= rem; e += 4) {
            int j0 = __builtin_amdgcn_readlane(myj, e);
            int j1 = __builtin_amdgcn_readlane(myj, e + 1);
            int j2 = __builtin_amdgcn_readlane(myj, e + 2);
            int j3 = __builtin_amdgcn_readlane(myj, e + 3);
            float p0 = rl_f(p, e),     p1 = rl_f(p, e + 1);
            float p2 = rl_f(p, e + 2), p3 = rl_f(p, e + 3);
            float v0 = h[(size_t)j0 * D + lane];
            float v1 = h[(size_t)j1 * D + lane];
            float v2 = h[(size_t)j2 * D + lane];
            float v3 = h[(size_t)j3 * D + lane];
            o += p0 * v0; o += p1 * v1; o += p2 * v2; o += p3 * v3;
        }
        for (; e < rem; ++e) {
            int j0 = __builtin_amdgcn_readlane(myj, e);
            float p0 = rl_f(p, e);
            o += p0 * h[(size_t)j0 * D + lane];
        }
    }

    float r = o / s + bias[lane];
    if (RELU) r = fmaxf(r, 0.f);
    out[(size_t)i * D + lane] = r;
}

// ---------------- launch ----------------

extern "C" void kernel_launch(void* const* d_in, const int* in_sizes, int n_in,
                              void* d_out, int out_size, void* d_ws, size_t ws_size,
                              hipStream_t stream)
{
    const float* embeds = (const float*)d_in[0];
    const int*   edges  = (const int*)d_in[1];   // [2, E] row-major
    const float* W1  = (const float*)d_in[2];
    const float* as1 = (const float*)d_in[3];
    const float* ad1 = (const float*)d_in[4];
    const float* b1  = (const float*)d_in[5];
    const float* W2  = (const float*)d_in[6];
    const float* as2 = (const float*)d_in[7];
    const float* ad2 = (const float*)d_in[8];
    const float* b2  = (const float*)d_in[9];

    int N = in_sizes[0] / D;
    int E = in_sizes[1] / 2;
    int total = E + N;

    char* ws = (char*)d_ws;
    float* h   = (float*)ws;  ws += (size_t)N * D * 4;
    float* x1  = (float*)ws;  ws += (size_t)N * D * 4;
    float* hs  = (float*)ws;  ws += (size_t)N * 4;
    float* hd  = (float*)ws;  ws += (size_t)N * 4;
    int* deg     = (int*)ws;  ws += (size_t)N * 4;
    int* rowptr  = (int*)ws;  ws += (size_t)N * 4;
    int* cursor  = (int*)ws;  ws += (size_t)N * 4;
    int* bsum    = (int*)ws;  ws += 1024 * 4;
    int* csr_src = (int*)ws;  ws += (size_t)total * 4;

    hipMemsetAsync(deg, 0, (size_t)N * 4, stream);

    const int tb = 256;
    int nbE = (total + tb - 1) / tb;
    int nbS = (N + tb - 1) / tb;      // 196 for N=50000 (fits scan2's 256)
    int nbN = (N + 3) / 4;
    int nbG = (N + 4 * NODES_PER_WAVE - 1) / (4 * NODES_PER_WAVE);

    hist_kernel<<<nbE, tb, 0, stream>>>(edges + E, E, N, deg);
    scan1_kernel<<<nbS, tb, 0, stream>>>(deg, rowptr, bsum, N);
    scan2_kernel<<<1, tb, 0, stream>>>(bsum, nbS);
    scan3_kernel<<<nbS, tb, 0, stream>>>(rowptr, bsum, cursor, N);
    scatter_kernel<<<nbE, tb, 0, stream>>>(edges, E, N, cursor, csr_src);

    // layer 1
    gemm_attn_kernel<<<nbG, 256, 0, stream>>>(embeds, W1, as1, ad1, h, hs, hd, N);
    gather_kernel<true><<<nbN, 256, 0, stream>>>(h, hs, hd, rowptr, deg, csr_src,
                                                 b1, x1, N);
    // layer 2
    gemm_attn_kernel<<<nbG, 256, 0, stream>>>(x1, W2, as2, ad2, h, hs, hd, N);
    gather_kernel<false><<<nbN, 256, 0, stream>>>(h, hs, hd, rowptr, deg, csr_src,
                                                  b2, (float*)d_out, N);
}

// Round 4
// 244.710 us; speedup vs baseline: 1.9165x; 1.0305x over previous
//
#include <hip/hip_runtime.h>

#define D 64
#define NGROUPS 8
#define BPG 128          // blocks per dst-range group

// ---------------- CSR build (dst-range partitioned, XCD-local writes) -------

__global__ __launch_bounds__(256) void hist_part_kernel(
    const int* __restrict__ dst, int E, int N, int* __restrict__ deg)
{
    int g  = blockIdx.x & (NGROUPS - 1);
    int bg = blockIdx.x >> 3;
    int lo = (int)((long long)g * N / NGROUPS);
    int hi = (int)((long long)(g + 1) * N / NGROUPS);
    int total = E + N;
    for (int e = bg * 256 + threadIdx.x; e < total; e += BPG * 256) {
        int d = (e < E) ? dst[e] : (e - E);
        if (d >= lo && d < hi) atomicAdd(&deg[d], 1);
    }
}

__global__ void scan1_kernel(const int* __restrict__ deg, int* __restrict__ rowptr,
                             int* __restrict__ bsum, int N) {
    __shared__ int tmp[256];
    int t = threadIdx.x;
    int idx = blockIdx.x * 256 + t;
    int v = (idx < N) ? deg[idx] : 0;
    tmp[t] = v;
    __syncthreads();
    for (int off = 1; off < 256; off <<= 1) {
        int add = (t >= off) ? tmp[t - off] : 0;
        __syncthreads();
        tmp[t] += add;
        __syncthreads();
    }
    if (idx < N) rowptr[idx] = tmp[t] - v;           // block-local exclusive
    if (t == 255) bsum[blockIdx.x] = tmp[255];       // block total
}

__global__ void scan2_kernel(int* __restrict__ bsum, int nb) {
    __shared__ int tmp[256];
    int t = threadIdx.x;
    int v = (t < nb) ? bsum[t] : 0;
    tmp[t] = v;
    __syncthreads();
    for (int off = 1; off < 256; off <<= 1) {
        int add = (t >= off) ? tmp[t - off] : 0;
        __syncthreads();
        tmp[t] += add;
        __syncthreads();
    }
    if (t < nb) bsum[t] = tmp[t] - v;                // exclusive block offsets
}

__global__ void scan3_kernel(int* __restrict__ rowptr, const int* __restrict__ bsum,
                             int* __restrict__ cursor, int N) {
    int idx = blockIdx.x * 256 + threadIdx.x;
    if (idx >= N) return;
    int v = rowptr[idx] + bsum[blockIdx.x];
    rowptr[idx] = v;
    cursor[idx] = v;
}

__global__ __launch_bounds__(256) void scatter_part_kernel(
    const int* __restrict__ edges, int E, int N,
    int* __restrict__ cursor, int* __restrict__ csr_src)
{
    int g  = blockIdx.x & (NGROUPS - 1);
    int bg = blockIdx.x >> 3;
    int lo = (int)((long long)g * N / NGROUPS);
    int hi = (int)((long long)(g + 1) * N / NGROUPS);
    int total = E + N;
    for (int e = bg * 256 + threadIdx.x; e < total; e += BPG * 256) {
        int d = (e < E) ? edges[E + e] : (e - E);
        if (d >= lo && d < hi) {
            int s = (e < E) ? edges[e] : d;
            int pos = atomicAdd(&cursor[d], 1);
            csr_src[pos] = s;
        }
    }
}

// ---------------- h = x @ W, plus per-node attention scalars ----------------
// Lane holds W column `lane` in 64 VGPRs (compile-time indexed). x-row read
// with uniform-address float4 loads (1 cacheline fetch, broadcast to lanes).

#define NODES_PER_WAVE 16

__global__ __launch_bounds__(256) void gemm_attn_kernel(
    const float* __restrict__ x, const float* __restrict__ W,
    const float* __restrict__ a_src, const float* __restrict__ a_dst,
    float* __restrict__ h, float* __restrict__ hs, float* __restrict__ hd, int N)
{
    int t = threadIdx.x;
    int wave = t >> 6;
    int lane = t & 63;

    float Wc[D];
    #pragma unroll
    for (int k = 0; k < D; ++k) Wc[k] = W[k * D + lane];   // coalesced per k
    float asv = a_src[lane], adv = a_dst[lane];

    int node0 = (blockIdx.x * 4 + wave) * NODES_PER_WAVE;
    for (int n = 0; n < NODES_PER_WAVE; ++n) {
        int i = node0 + n;
        if (i >= N) break;                 // wave-uniform

        const float4* xr = (const float4*)(x + (size_t)i * D);
        float a0 = 0.f, a1 = 0.f, a2 = 0.f, a3 = 0.f;
        #pragma unroll
        for (int kk = 0; kk < D / 4; ++kk) {
            float4 xv = xr[kk];            // uniform-address broadcast load
            a0 = fmaf(xv.x, Wc[4 * kk + 0], a0);
            a1 = fmaf(xv.y, Wc[4 * kk + 1], a1);
            a2 = fmaf(xv.z, Wc[4 * kk + 2], a2);
            a3 = fmaf(xv.w, Wc[4 * kk + 3], a3);
        }
        float acc = (a0 + a1) + (a2 + a3);

        h[(size_t)i * D + lane] = acc;

        float vs = acc * asv;
        float vd = acc * adv;
        #pragma unroll
        for (int off = 32; off > 0; off >>= 1) {
            vs += __shfl_xor(vs, off);
            vd += __shfl_xor(vd, off);
        }
        if (lane == 0) { hs[i] = vs; hd[i] = vd; }
    }
}

// ---------------- segment softmax + aggregation (one wave per dst node) -----

__device__ __forceinline__ float rl_f(float v, int l) {
    return __uint_as_float(__builtin_amdgcn_readlane(__float_as_uint(v), l));
}

template <bool RELU>
__global__ __launch_bounds__(256) void gather_kernel(
    const float* __restrict__ h, const float* __restrict__ hs,
    const float* __restrict__ hd,
    const int* __restrict__ rowptr, const int* __restrict__ deg,
    const int* __restrict__ csr_src,
    const float* __restrict__ bias, float* __restrict__ out, int N)
{
    int t = threadIdx.x;
    int wave = t >> 6;
    int lane = t & 63;
    int i = blockIdx.x * 4 + wave;
    if (i >= N) return;

    int start = rowptr[i];
    int cnt = deg[i];
    float hdv = hd[i];

    float m = -1e30f, s = 0.f, o = 0.f;

    for (int base = 0; base < cnt; base += 64) {
        int rem = cnt - base; if (rem > 64) rem = 64;

        int myj = 0; float myl = -1e30f;
        if (lane < rem) {
            myj = csr_src[start + base + lane];
            float l = hs[myj] + hdv;
            myl = (l > 0.f) ? l : 0.2f * l;
        }

        // wave max of this chunk
        float cm = myl;
        #pragma unroll
        for (int off = 32; off; off >>= 1) cm = fmaxf(cm, __shfl_xor(cm, off));
        if (cm > m) {                       // wave-uniform rescale (exact)
            float sc = __expf(m - cm);
            s *= sc; o *= sc; m = cm;
        }

        float p = __expf(myl - m);          // lanes >= rem: exp(-1e30) == 0
        float cs = p;
        #pragma unroll
        for (int off = 32; off; off >>= 1) cs += __shfl_xor(cs, off);
        s += cs;

        // weighted accumulation: broadcast (j, p) per edge, gather h row
        int e = 0;
        for (; e + 4 <= rem; e += 4) {
            int j0 = __builtin_amdgcn_readlane(myj, e);
            int j1 = __builtin_amdgcn_readlane(myj, e + 1);
            int j2 = __builtin_amdgcn_readlane(myj, e + 2);
            int j3 = __builtin_amdgcn_readlane(myj, e + 3);
            float p0 = rl_f(p, e),     p1 = rl_f(p, e + 1);
            float p2 = rl_f(p, e + 2), p3 = rl_f(p, e + 3);
            float v0 = h[(size_t)j0 * D + lane];
            float v1 = h[(size_t)j1 * D + lane];
            float v2 = h[(size_t)j2 * D + lane];
            float v3 = h[(size_t)j3 * D + lane];
            o += p0 * v0; o += p1 * v1; o += p2 * v2; o += p3 * v3;
        }
        for (; e < rem; ++e) {
            int j0 = __builtin_amdgcn_readlane(myj, e);
            float p0 = rl_f(p, e);
            o += p0 * h[(size_t)j0 * D + lane];
        }
    }

    float r = o / s + bias[lane];
    if (RELU) r = fmaxf(r, 0.f);
    out[(size_t)i * D + lane] = r;
}

// ---------------- launch ----------------

extern "C" void kernel_launch(void* const* d_in, const int* in_sizes, int n_in,
                              void* d_out, int out_size, void* d_ws, size_t ws_size,
                              hipStream_t stream)
{
    const float* embeds = (const float*)d_in[0];
    const int*   edges  = (const int*)d_in[1];   // [2, E] row-major
    const float* W1  = (const float*)d_in[2];
    const float* as1 = (const float*)d_in[3];
    const float* ad1 = (const float*)d_in[4];
    const float* b1  = (const float*)d_in[5];
    const float* W2  = (const float*)d_in[6];
    const float* as2 = (const float*)d_in[7];
    const float* ad2 = (const float*)d_in[8];
    const float* b2  = (const float*)d_in[9];

    int N = in_sizes[0] / D;
    int E = in_sizes[1] / 2;
    int total = E + N;

    char* ws = (char*)d_ws;
    float* h   = (float*)ws;  ws += (size_t)N * D * 4;
    float* x1  = (float*)ws;  ws += (size_t)N * D * 4;
    float* hs  = (float*)ws;  ws += (size_t)N * 4;
    float* hd  = (float*)ws;  ws += (size_t)N * 4;
    int* deg     = (int*)ws;  ws += (size_t)N * 4;
    int* rowptr  = (int*)ws;  ws += (size_t)N * 4;
    int* cursor  = (int*)ws;  ws += (size_t)N * 4;
    int* bsum    = (int*)ws;  ws += 1024 * 4;
    int* csr_src = (int*)ws;  ws += (size_t)total * 4;

    hipMemsetAsync(deg, 0, (size_t)N * 4, stream);

    const int tb = 256;
    int nbS = (N + tb - 1) / tb;      // 196 for N=50000 (fits scan2's 256)
    int nbN = (N + 3) / 4;
    int nbG = (N + 4 * NODES_PER_WAVE - 1) / (4 * NODES_PER_WAVE);

    hist_part_kernel<<<NGROUPS * BPG, tb, 0, stream>>>(edges + E, E, N, deg);
    scan1_kernel<<<nbS, tb, 0, stream>>>(deg, rowptr, bsum, N);
    scan2_kernel<<<1, tb, 0, stream>>>(bsum, nbS);
    scan3_kernel<<<nbS, tb, 0, stream>>>(rowptr, bsum, cursor, N);
    scatter_part_kernel<<<NGROUPS * BPG, tb, 0, stream>>>(edges, E, N, cursor, csr_src);

    // layer 1
    gemm_attn_kernel<<<nbG, 256, 0, stream>>>(embeds, W1, as1, ad1, h, hs, hd, N);
    gather_kernel<true><<<nbN, 256, 0, stream>>>(h, hs, hd, rowptr, deg, csr_src,
                                                 b1, x1, N);
    // layer 2
    gemm_attn_kernel<<<nbG, 256, 0, stream>>>(x1, W2, as2, ad2, h, hs, hd, N);
    gather_kernel<false><<<nbN, 256, 0, stream>>>(h, hs, hd, rowptr, deg, csr_src,
                                                  b2, (float*)d_out, N);
}

// Round 5
// 180.399 us; speedup vs baseline: 2.5997x; 1.3565x over previous
//
#include <hip/hip_runtime.h>

#define D 64
#define NGROUPS 8
#define BPG 128          // blocks per dst-range group

typedef __attribute__((ext_vector_type(8))) __bf16 bf16x8;
typedef __attribute__((ext_vector_type(4))) float f32x4;

__device__ __forceinline__ unsigned short f2b(float f) {   // f32 -> bf16 RNE
    unsigned int u = __float_as_uint(f);
    return (unsigned short)((u + 0x7fffu + ((u >> 16) & 1u)) >> 16);
}
__device__ __forceinline__ float rl_f(float v, int l) {
    return __uint_as_float(__builtin_amdgcn_readlane(__float_as_uint(v), l));
}

// ---------------- CSR build (dst-range partitioned, XCD-local writes) -------

__global__ __launch_bounds__(256) void hist_part_kernel(
    const int* __restrict__ dst, int E, int N, int* __restrict__ deg)
{
    int g  = blockIdx.x & (NGROUPS - 1);
    int bg = blockIdx.x >> 3;
    int lo = (int)((long long)g * N / NGROUPS);
    int hi = (int)((long long)(g + 1) * N / NGROUPS);
    int total = E + N;
    for (int e = bg * 256 + threadIdx.x; e < total; e += BPG * 256) {
        int d = (e < E) ? dst[e] : (e - E);
        if (d >= lo && d < hi) atomicAdd(&deg[d], 1);
    }
}

__global__ void scan1_kernel(const int* __restrict__ deg, int* __restrict__ rowptr,
                             int* __restrict__ bsum, int N) {
    __shared__ int tmp[256];
    int t = threadIdx.x;
    int idx = blockIdx.x * 256 + t;
    int v = (idx < N) ? deg[idx] : 0;
    tmp[t] = v;
    __syncthreads();
    for (int off = 1; off < 256; off <<= 1) {
        int add = (t >= off) ? tmp[t - off] : 0;
        __syncthreads();
        tmp[t] += add;
        __syncthreads();
    }
    if (idx < N) rowptr[idx] = tmp[t] - v;
    if (t == 255) bsum[blockIdx.x] = tmp[255];
}

__global__ void scan2_kernel(int* __restrict__ bsum, int nb) {
    __shared__ int tmp[256];
    int t = threadIdx.x;
    int v = (t < nb) ? bsum[t] : 0;
    tmp[t] = v;
    __syncthreads();
    for (int off = 1; off < 256; off <<= 1) {
        int add = (t >= off) ? tmp[t - off] : 0;
        __syncthreads();
        tmp[t] += add;
        __syncthreads();
    }
    if (t < nb) bsum[t] = tmp[t] - v;
}

__global__ void scan3_kernel(int* __restrict__ rowptr, const int* __restrict__ bsum,
                             int* __restrict__ cursor, int N) {
    int idx = blockIdx.x * 256 + threadIdx.x;
    if (idx >= N) return;
    int v = rowptr[idx] + bsum[blockIdx.x];
    rowptr[idx] = v;
    cursor[idx] = v;
}

__global__ __launch_bounds__(256) void scatter_part_kernel(
    const int* __restrict__ edges, int E, int N,
    int* __restrict__ cursor, int* __restrict__ csr_src)
{
    int g  = blockIdx.x & (NGROUPS - 1);
    int bg = blockIdx.x >> 3;
    int lo = (int)((long long)g * N / NGROUPS);
    int hi = (int)((long long)(g + 1) * N / NGROUPS);
    int total = E + N;
    for (int e = bg * 256 + threadIdx.x; e < total; e += BPG * 256) {
        int d = (e < E) ? edges[E + e] : (e - E);
        if (d >= lo && d < hi) {
            int s = (e < E) ? edges[e] : d;
            int pos = atomicAdd(&cursor[d], 1);
            csr_src[pos] = s;
        }
    }
}

// ---------------- h = x @ W via MFMA (bf16), + attention scalars ------------
// Wave computes 16 rows x 64 cols: 8x mfma_f32_16x16x32_bf16.
// A lane layout: row = l&15, k = (l>>4)*8 + e (8 contiguous bf16 = dwordx4).
// B lane layout: col = l&15, k = (l>>4)*8 + e.
// C lane layout: col = l&15, row = (l>>4)*4 + reg.  [m89 verified]

template <bool SRC_F32>
__global__ __launch_bounds__(256) void gemm_mfma_kernel(
    const void* __restrict__ xin, const float* __restrict__ W,
    const float* __restrict__ a_src, const float* __restrict__ a_dst,
    unsigned short* __restrict__ hb,     // [N][64] bf16 out
    float* __restrict__ hs, float* __restrict__ hd, int N)
{
    int t = threadIdx.x;
    int wave = t >> 6;
    int lane = t & 63;
    int lr = lane & 15;
    int lg = lane >> 4;

    int row0 = blockIdx.x * 64 + wave * 16;

    // B fragments: W[k][n], need col c*16+lr, k = kk*32 + lg*8 + e
    bf16x8 bfr[4][2];
    #pragma unroll
    for (int c = 0; c < 4; ++c)
        #pragma unroll
        for (int kk = 0; kk < 2; ++kk) {
            union { unsigned short u[8]; bf16x8 v; } tmp;
            #pragma unroll
            for (int e = 0; e < 8; ++e)
                tmp.u[e] = f2b(W[(kk * 32 + lg * 8 + e) * 64 + c * 16 + lr]);
            bfr[c][kk] = tmp.v;
        }

    // A fragments: x[arow][kk*32 + lg*8 .. +7]
    int arow = row0 + lr; if (arow >= N) arow = N - 1;
    bf16x8 afr[2];
    if constexpr (SRC_F32) {
        const float* xf = (const float*)xin;
        #pragma unroll
        for (int kk = 0; kk < 2; ++kk) {
            const float4* pr = (const float4*)(xf + (size_t)arow * D + kk * 32 + lg * 8);
            float4 v0 = pr[0], v1 = pr[1];
            union { unsigned short u[8]; bf16x8 v; } tmp;
            tmp.u[0] = f2b(v0.x); tmp.u[1] = f2b(v0.y);
            tmp.u[2] = f2b(v0.z); tmp.u[3] = f2b(v0.w);
            tmp.u[4] = f2b(v1.x); tmp.u[5] = f2b(v1.y);
            tmp.u[6] = f2b(v1.z); tmp.u[7] = f2b(v1.w);
            afr[kk] = tmp.v;
        }
    } else {
        const unsigned short* xb = (const unsigned short*)xin;
        #pragma unroll
        for (int kk = 0; kk < 2; ++kk) {
            union { uint4 r; bf16x8 v; } tmp;
            tmp.r = *(const uint4*)(xb + (size_t)arow * D + kk * 32 + lg * 8);
            afr[kk] = tmp.v;
        }
    }

    f32x4 acc[4];
    #pragma unroll
    for (int c = 0; c < 4; ++c) acc[c] = (f32x4){0.f, 0.f, 0.f, 0.f};

    #pragma unroll
    for (int kk = 0; kk < 2; ++kk)
        #pragma unroll
        for (int c = 0; c < 4; ++c)
            acc[c] = __builtin_amdgcn_mfma_f32_16x16x32_bf16(afr[kk], bfr[c][kk],
                                                             acc[c], 0, 0, 0);

    float asv[4], adv[4];
    #pragma unroll
    for (int c = 0; c < 4; ++c) {
        asv[c] = a_src[c * 16 + lr];
        adv[c] = a_dst[c * 16 + lr];
    }

    #pragma unroll
    for (int r = 0; r < 4; ++r) {
        int row = row0 + lg * 4 + r;
        float vs = 0.f, vd = 0.f;
        #pragma unroll
        for (int c = 0; c < 4; ++c) {
            float hv = acc[c][r];
            if (row < N) hb[(size_t)row * D + c * 16 + lr] = f2b(hv);
            vs = fmaf(hv, asv[c], vs);
            vd = fmaf(hv, adv[c], vd);
        }
        #pragma unroll
        for (int off = 8; off; off >>= 1) {      // reduce over lr (16 lanes)
            vs += __shfl_xor(vs, off);
            vd += __shfl_xor(vd, off);
        }
        if (lr == 0 && row < N) { hs[row] = vs; hd[row] = vd; }
    }
}

// ---------------- segment softmax + aggregation (one wave per dst node) -----
// Logits: lane-parallel over 64 edges/chunk. Aggregation: two 32-lane halves
// each own one edge; lane handles a bf16 feature pair (h stored bf16).

template <bool RELU>
__global__ __launch_bounds__(256) void gather_kernel(
    const unsigned int* __restrict__ hb32,   // h as bf16 pairs [N][32]
    const float* __restrict__ hs, const float* __restrict__ hd,
    const int* __restrict__ rowptr, const int* __restrict__ deg,
    const int* __restrict__ csr_src,
    const float* __restrict__ bias, void* __restrict__ outv, int N)
{
    int t = threadIdx.x;
    int wave = t >> 6;
    int lane = t & 63;
    int i = blockIdx.x * 4 + wave;
    if (i >= N) return;

    int half = lane >> 5;
    int f = lane & 31;          // feature pair (2f, 2f+1)

    int start = rowptr[i];
    int cnt = deg[i];
    float hdv = hd[i];

    float m = -1e30f, s = 0.f, o0 = 0.f, o1 = 0.f;

    for (int base = 0; base < cnt; base += 64) {
        int rem = cnt - base; if (rem > 64) rem = 64;

        int myj = 0; float myl = -1e30f;
        if (lane < rem) {
            myj = csr_src[start + base + lane];
            float l = hs[myj] + hdv;
            myl = (l > 0.f) ? l : 0.2f * l;
        }

        float cm = myl;
        #pragma unroll
        for (int off = 32; off; off >>= 1) cm = fmaxf(cm, __shfl_xor(cm, off));
        if (cm > m) {
            float sc = __expf(m - cm);
            s *= sc; o0 *= sc; o1 *= sc; m = cm;
        }

        float p = __expf(myl - m);
        float cs = p;
        #pragma unroll
        for (int off = 32; off; off >>= 1) cs += __shfl_xor(cs, off);
        s += cs;

        int e = 0;
        for (; e + 4 <= rem; e += 4) {
            int jA0 = __builtin_amdgcn_readlane(myj, e);
            int jB0 = __builtin_amdgcn_readlane(myj, e + 1);
            int jA1 = __builtin_amdgcn_readlane(myj, e + 2);
            int jB1 = __builtin_amdgcn_readlane(myj, e + 3);
            float pA0 = rl_f(p, e),     pB0 = rl_f(p, e + 1);
            float pA1 = rl_f(p, e + 2), pB1 = rl_f(p, e + 3);
            int j0 = half ? jB0 : jA0;  float pp0 = half ? pB0 : pA0;
            int j1 = half ? jB1 : jA1;  float pp1 = half ? pB1 : pA1;
            unsigned int hv0 = hb32[(size_t)j0 * 32 + f];
            unsigned int hv1 = hb32[(size_t)j1 * 32 + f];
            o0 = fmaf(pp0, __uint_as_float(hv0 << 16), o0);
            o1 = fmaf(pp0, __uint_as_float(hv0 & 0xffff0000u), o1);
            o0 = fmaf(pp1, __uint_as_float(hv1 << 16), o0);
            o1 = fmaf(pp1, __uint_as_float(hv1 & 0xffff0000u), o1);
        }
        for (; e < rem; e += 2) {
            int jA = __builtin_amdgcn_readlane(myj, e);
            float pA = rl_f(p, e);
            int jB = jA; float pB = 0.f;
            if (e + 1 < rem) {
                jB = __builtin_amdgcn_readlane(myj, e + 1);
                pB = rl_f(p, e + 1);
            }
            int j = half ? jB : jA;  float pp = half ? pB : pA;
            unsigned int hv = hb32[(size_t)j * 32 + f];
            o0 = fmaf(pp, __uint_as_float(hv << 16), o0);
            o1 = fmaf(pp, __uint_as_float(hv & 0xffff0000u), o1);
        }
    }

    o0 += __shfl_xor(o0, 32);
    o1 += __shfl_xor(o1, 32);

    if (half == 0) {
        float2 bv = ((const float2*)bias)[f];
        float r0 = o0 / s + bv.x;
        float r1 = o1 / s + bv.y;
        if (RELU) {
            r0 = fmaxf(r0, 0.f); r1 = fmaxf(r1, 0.f);
            unsigned int pk = ((unsigned int)f2b(r1) << 16) | f2b(r0);
            ((unsigned int*)outv)[(size_t)i * 32 + f] = pk;
        } else {
            ((float2*)outv)[(size_t)i * 32 + f] = make_float2(r0, r1);
        }
    }
}

// ---------------- launch ----------------

extern "C" void kernel_launch(void* const* d_in, const int* in_sizes, int n_in,
                              void* d_out, int out_size, void* d_ws, size_t ws_size,
                              hipStream_t stream)
{
    const float* embeds = (const float*)d_in[0];
    const int*   edges  = (const int*)d_in[1];   // [2, E] row-major
    const float* W1  = (const float*)d_in[2];
    const float* as1 = (const float*)d_in[3];
    const float* ad1 = (const float*)d_in[4];
    const float* b1  = (const float*)d_in[5];
    const float* W2  = (const float*)d_in[6];
    const float* as2 = (const float*)d_in[7];
    const float* ad2 = (const float*)d_in[8];
    const float* b2  = (const float*)d_in[9];

    int N = in_sizes[0] / D;
    int E = in_sizes[1] / 2;
    int total = E + N;

    char* ws = (char*)d_ws;
    unsigned short* hb  = (unsigned short*)ws;  ws += (size_t)N * D * 2;
    unsigned short* x1b = (unsigned short*)ws;  ws += (size_t)N * D * 2;
    float* hs  = (float*)ws;  ws += (size_t)N * 4;
    float* hd  = (float*)ws;  ws += (size_t)N * 4;
    int* deg     = (int*)ws;  ws += (size_t)N * 4;
    int* rowptr  = (int*)ws;  ws += (size_t)N * 4;
    int* cursor  = (int*)ws;  ws += (size_t)N * 4;
    int* bsum    = (int*)ws;  ws += 1024 * 4;
    int* csr_src = (int*)ws;  ws += (size_t)total * 4;

    hipMemsetAsync(deg, 0, (size_t)N * 4, stream);

    const int tb = 256;
    int nbS = (N + tb - 1) / tb;
    int nbN = (N + 3) / 4;
    int nbM = (N + 63) / 64;

    hist_part_kernel<<<NGROUPS * BPG, tb, 0, stream>>>(edges + E, E, N, deg);
    scan1_kernel<<<nbS, tb, 0, stream>>>(deg, rowptr, bsum, N);
    scan2_kernel<<<1, tb, 0, stream>>>(bsum, nbS);
    scan3_kernel<<<nbS, tb, 0, stream>>>(rowptr, bsum, cursor, N);
    scatter_part_kernel<<<NGROUPS * BPG, tb, 0, stream>>>(edges, E, N, cursor, csr_src);

    // layer 1 (f32 embeds in, bf16 x1 out with relu)
    gemm_mfma_kernel<true><<<nbM, tb, 0, stream>>>(embeds, W1, as1, ad1,
                                                   hb, hs, hd, N);
    gather_kernel<true><<<nbN, tb, 0, stream>>>((const unsigned int*)hb, hs, hd,
                                                rowptr, deg, csr_src, b1, x1b, N);
    // layer 2 (bf16 x1 in, f32 out)
    gemm_mfma_kernel<false><<<nbM, tb, 0, stream>>>(x1b, W2, as2, ad2,
                                                    hb, hs, hd, N);
    gather_kernel<false><<<nbN, tb, 0, stream>>>((const unsigned int*)hb, hs, hd,
                                                 rowptr, deg, csr_src, b2, d_out, N);
}

// Round 6
// 179.581 us; speedup vs baseline: 2.6115x; 1.0046x over previous
//
#include <hip/hip_runtime.h>

#define D 64
#define NGROUPS 8
#define BPG 128          // blocks per dst-range group

typedef __attribute__((ext_vector_type(8))) __bf16 bf16x8;
typedef __attribute__((ext_vector_type(4))) float f32x4;

__device__ __forceinline__ unsigned short f2b(float f) {   // f32 -> bf16 RNE
    unsigned int u = __float_as_uint(f);
    return (unsigned short)((u + 0x7fffu + ((u >> 16) & 1u)) >> 16);
}
__device__ __forceinline__ float rl_f(float v, int l) {
    return __uint_as_float(__builtin_amdgcn_readlane(__float_as_uint(v), l));
}

// ---------------- zero deg (runtime fillBuffer is ~44us for 200KB!) --------

__global__ __launch_bounds__(256) void zero_kernel(int* __restrict__ p, int n) {
    int idx = blockIdx.x * 256 + threadIdx.x;
    if (idx < n) p[idx] = 0;
}

// ---------------- CSR build (dst-range partitioned, XCD-local writes) -------

__global__ __launch_bounds__(256) void hist_part_kernel(
    const int* __restrict__ dst, int E, int N, int* __restrict__ deg)
{
    int g  = blockIdx.x & (NGROUPS - 1);
    int bg = blockIdx.x >> 3;
    int lo = (int)((long long)g * N / NGROUPS);
    int hi = (int)((long long)(g + 1) * N / NGROUPS);
    int total = E + N;
    for (int e = bg * 256 + threadIdx.x; e < total; e += BPG * 256) {
        int d = (e < E) ? dst[e] : (e - E);
        if (d >= lo && d < hi) atomicAdd(&deg[d], 1);
    }
}

__global__ void scan1_kernel(const int* __restrict__ deg, int* __restrict__ rowptr,
                             int* __restrict__ bsum, int N) {
    __shared__ int tmp[256];
    int t = threadIdx.x;
    int idx = blockIdx.x * 256 + t;
    int v = (idx < N) ? deg[idx] : 0;
    tmp[t] = v;
    __syncthreads();
    for (int off = 1; off < 256; off <<= 1) {
        int add = (t >= off) ? tmp[t - off] : 0;
        __syncthreads();
        tmp[t] += add;
        __syncthreads();
    }
    if (idx < N) rowptr[idx] = tmp[t] - v;
    if (t == 255) bsum[blockIdx.x] = tmp[255];
}

__global__ void scan2_kernel(int* __restrict__ bsum, int nb) {
    __shared__ int tmp[256];
    int t = threadIdx.x;
    int v = (t < nb) ? bsum[t] : 0;
    tmp[t] = v;
    __syncthreads();
    for (int off = 1; off < 256; off <<= 1) {
        int add = (t >= off) ? tmp[t - off] : 0;
        __syncthreads();
        tmp[t] += add;
        __syncthreads();
    }
    if (t < nb) bsum[t] = tmp[t] - v;
}

__global__ void scan3_kernel(int* __restrict__ rowptr, const int* __restrict__ bsum,
                             int* __restrict__ cursor, int N) {
    int idx = blockIdx.x * 256 + threadIdx.x;
    if (idx >= N) return;
    int v = rowptr[idx] + bsum[blockIdx.x];
    rowptr[idx] = v;
    cursor[idx] = v;
}

__global__ __launch_bounds__(256) void scatter_part_kernel(
    const int* __restrict__ edges, int E, int N,
    int* __restrict__ cursor, int* __restrict__ csr_src)
{
    int g  = blockIdx.x & (NGROUPS - 1);
    int bg = blockIdx.x >> 3;
    int lo = (int)((long long)g * N / NGROUPS);
    int hi = (int)((long long)(g + 1) * N / NGROUPS);
    int total = E + N;
    for (int e = bg * 256 + threadIdx.x; e < total; e += BPG * 256) {
        int d = (e < E) ? edges[E + e] : (e - E);
        if (d >= lo && d < hi) {
            int s = (e < E) ? edges[e] : d;
            int pos = atomicAdd(&cursor[d], 1);
            csr_src[pos] = s;
        }
    }
}

// ---------------- h = x @ W via MFMA (bf16), + attention scalars ------------
// Wave computes 16 rows x 64 cols: 8x mfma_f32_16x16x32_bf16.
// A lane layout: row = l&15, k = (l>>4)*8 + e (8 contiguous bf16 = dwordx4).
// C lane layout: col = l&15, row = (l>>4)*4 + reg.  [m89 verified]

template <bool SRC_F32>
__global__ __launch_bounds__(256) void gemm_mfma_kernel(
    const void* __restrict__ xin, const float* __restrict__ W,
    const float* __restrict__ a_src, const float* __restrict__ a_dst,
    unsigned short* __restrict__ hb,     // [N][64] bf16 out
    float* __restrict__ hs, float* __restrict__ hd, int N)
{
    int t = threadIdx.x;
    int wave = t >> 6;
    int lane = t & 63;
    int lr = lane & 15;
    int lg = lane >> 4;

    int row0 = blockIdx.x * 64 + wave * 16;

    // B fragments: W[k][n], need col c*16+lr, k = kk*32 + lg*8 + e
    bf16x8 bfr[4][2];
    #pragma unroll
    for (int c = 0; c < 4; ++c)
        #pragma unroll
        for (int kk = 0; kk < 2; ++kk) {
            union { unsigned short u[8]; bf16x8 v; } tmp;
            #pragma unroll
            for (int e = 0; e < 8; ++e)
                tmp.u[e] = f2b(W[(kk * 32 + lg * 8 + e) * 64 + c * 16 + lr]);
            bfr[c][kk] = tmp.v;
        }

    // A fragments: x[arow][kk*32 + lg*8 .. +7]
    int arow = row0 + lr; if (arow >= N) arow = N - 1;
    bf16x8 afr[2];
    if constexpr (SRC_F32) {
        const float* xf = (const float*)xin;
        #pragma unroll
        for (int kk = 0; kk < 2; ++kk) {
            const float4* pr = (const float4*)(xf + (size_t)arow * D + kk * 32 + lg * 8);
            float4 v0 = pr[0], v1 = pr[1];
            union { unsigned short u[8]; bf16x8 v; } tmp;
            tmp.u[0] = f2b(v0.x); tmp.u[1] = f2b(v0.y);
            tmp.u[2] = f2b(v0.z); tmp.u[3] = f2b(v0.w);
            tmp.u[4] = f2b(v1.x); tmp.u[5] = f2b(v1.y);
            tmp.u[6] = f2b(v1.z); tmp.u[7] = f2b(v1.w);
            afr[kk] = tmp.v;
        }
    } else {
        const unsigned short* xb = (const unsigned short*)xin;
        #pragma unroll
        for (int kk = 0; kk < 2; ++kk) {
            union { uint4 r; bf16x8 v; } tmp;
            tmp.r = *(const uint4*)(xb + (size_t)arow * D + kk * 32 + lg * 8);
            afr[kk] = tmp.v;
        }
    }

    f32x4 acc[4];
    #pragma unroll
    for (int c = 0; c < 4; ++c) acc[c] = (f32x4){0.f, 0.f, 0.f, 0.f};

    #pragma unroll
    for (int kk = 0; kk < 2; ++kk)
        #pragma unroll
        for (int c = 0; c < 4; ++c)
            acc[c] = __builtin_amdgcn_mfma_f32_16x16x32_bf16(afr[kk], bfr[c][kk],
                                                             acc[c], 0, 0, 0);

    float asv[4], adv[4];
    #pragma unroll
    for (int c = 0; c < 4; ++c) {
        asv[c] = a_src[c * 16 + lr];
        adv[c] = a_dst[c * 16 + lr];
    }

    #pragma unroll
    for (int r = 0; r < 4; ++r) {
        int row = row0 + lg * 4 + r;
        float vs = 0.f, vd = 0.f;
        #pragma unroll
        for (int c = 0; c < 4; ++c) {
            float hv = acc[c][r];
            if (row < N) hb[(size_t)row * D + c * 16 + lr] = f2b(hv);
            vs = fmaf(hv, asv[c], vs);
            vd = fmaf(hv, adv[c], vd);
        }
        #pragma unroll
        for (int off = 8; off; off >>= 1) {      // reduce over lr (16 lanes)
            vs += __shfl_xor(vs, off);
            vd += __shfl_xor(vd, off);
        }
        if (lr == 0 && row < N) { hs[row] = vs; hd[row] = vd; }
    }
}

// ---------------- segment softmax + aggregation (one wave per dst node) -----
// Logits: lane-parallel over 64 edges/chunk. Aggregation: two 32-lane halves
// each own one edge; lane handles a bf16 feature pair (h stored bf16).

template <bool RELU>
__global__ __launch_bounds__(256) void gather_kernel(
    const unsigned int* __restrict__ hb32,   // h as bf16 pairs [N][32]
    const float* __restrict__ hs, const float* __restrict__ hd,
    const int* __restrict__ rowptr, const int* __restrict__ deg,
    const int* __restrict__ csr_src,
    const float* __restrict__ bias, void* __restrict__ outv, int N)
{
    int t = threadIdx.x;
    int wave = t >> 6;
    int lane = t & 63;
    int i = blockIdx.x * 4 + wave;
    if (i >= N) return;

    int half = lane >> 5;
    int f = lane & 31;          // feature pair (2f, 2f+1)

    int start = rowptr[i];
    int cnt = deg[i];
    float hdv = hd[i];

    float m = -1e30f, s = 0.f, o0 = 0.f, o1 = 0.f;

    for (int base = 0; base < cnt; base += 64) {
        int rem = cnt - base; if (rem > 64) rem = 64;

        int myj = 0; float myl = -1e30f;
        if (lane < rem) {
            myj = csr_src[start + base + lane];
            float l = hs[myj] + hdv;
            myl = (l > 0.f) ? l : 0.2f * l;
        }

        float cm = myl;
        #pragma unroll
        for (int off = 32; off; off >>= 1) cm = fmaxf(cm, __shfl_xor(cm, off));
        if (cm > m) {
            float sc = __expf(m - cm);
            s *= sc; o0 *= sc; o1 *= sc; m = cm;
        }

        float p = __expf(myl - m);
        float cs = p;
        #pragma unroll
        for (int off = 32; off; off >>= 1) cs += __shfl_xor(cs, off);
        s += cs;

        int e = 0;
        for (; e + 4 <= rem; e += 4) {
            int jA0 = __builtin_amdgcn_readlane(myj, e);
            int jB0 = __builtin_amdgcn_readlane(myj, e + 1);
            int jA1 = __builtin_amdgcn_readlane(myj, e + 2);
            int jB1 = __builtin_amdgcn_readlane(myj, e + 3);
            float pA0 = rl_f(p, e),     pB0 = rl_f(p, e + 1);
            float pA1 = rl_f(p, e + 2), pB1 = rl_f(p, e + 3);
            int j0 = half ? jB0 : jA0;  float pp0 = half ? pB0 : pA0;
            int j1 = half ? jB1 : jA1;  float pp1 = half ? pB1 : pA1;
            unsigned int hv0 = hb32[(size_t)j0 * 32 + f];
            unsigned int hv1 = hb32[(size_t)j1 * 32 + f];
            o0 = fmaf(pp0, __uint_as_float(hv0 << 16), o0);
            o1 = fmaf(pp0, __uint_as_float(hv0 & 0xffff0000u), o1);
            o0 = fmaf(pp1, __uint_as_float(hv1 << 16), o0);
            o1 = fmaf(pp1, __uint_as_float(hv1 & 0xffff0000u), o1);
        }
        for (; e < rem; e += 2) {
            int jA = __builtin_amdgcn_readlane(myj, e);
            float pA = rl_f(p, e);
            int jB = jA; float pB = 0.f;
            if (e + 1 < rem) {
                jB = __builtin_amdgcn_readlane(myj, e + 1);
                pB = rl_f(p, e + 1);
            }
            int j = half ? jB : jA;  float pp = half ? pB : pA;
            unsigned int hv = hb32[(size_t)j * 32 + f];
            o0 = fmaf(pp, __uint_as_float(hv << 16), o0);
            o1 = fmaf(pp, __uint_as_float(hv & 0xffff0000u), o1);
        }
    }

    o0 += __shfl_xor(o0, 32);
    o1 += __shfl_xor(o1, 32);

    if (half == 0) {
        float2 bv = ((const float2*)bias)[f];
        float r0 = o0 / s + bv.x;
        float r1 = o1 / s + bv.y;
        if (RELU) {
            r0 = fmaxf(r0, 0.f); r1 = fmaxf(r1, 0.f);
            unsigned int pk = ((unsigned int)f2b(r1) << 16) | f2b(r0);
            ((unsigned int*)outv)[(size_t)i * 32 + f] = pk;
        } else {
            ((float2*)outv)[(size_t)i * 32 + f] = make_float2(r0, r1);
        }
    }
}

// ---------------- launch ----------------

extern "C" void kernel_launch(void* const* d_in, const int* in_sizes, int n_in,
                              void* d_out, int out_size, void* d_ws, size_t ws_size,
                              hipStream_t stream)
{
    const float* embeds = (const float*)d_in[0];
    const int*   edges  = (const int*)d_in[1];   // [2, E] row-major
    const float* W1  = (const float*)d_in[2];
    const float* as1 = (const float*)d_in[3];
    const float* ad1 = (const float*)d_in[4];
    const float* b1  = (const float*)d_in[5];
    const float* W2  = (const float*)d_in[6];
    const float* as2 = (const float*)d_in[7];
    const float* ad2 = (const float*)d_in[8];
    const float* b2  = (const float*)d_in[9];

    int N = in_sizes[0] / D;
    int E = in_sizes[1] / 2;
    int total = E + N;

    char* ws = (char*)d_ws;
    unsigned short* hb  = (unsigned short*)ws;  ws += (size_t)N * D * 2;
    unsigned short* x1b = (unsigned short*)ws;  ws += (size_t)N * D * 2;
    float* hs  = (float*)ws;  ws += (size_t)N * 4;
    float* hd  = (float*)ws;  ws += (size_t)N * 4;
    int* deg     = (int*)ws;  ws += (size_t)N * 4;
    int* rowptr  = (int*)ws;  ws += (size_t)N * 4;
    int* cursor  = (int*)ws;  ws += (size_t)N * 4;
    int* bsum    = (int*)ws;  ws += 1024 * 4;
    int* csr_src = (int*)ws;  ws += (size_t)total * 4;

    const int tb = 256;
    int nbS = (N + tb - 1) / tb;
    int nbN = (N + 3) / 4;
    int nbM = (N + 63) / 64;

    zero_kernel<<<nbS, tb, 0, stream>>>(deg, N);
    hist_part_kernel<<<NGROUPS * BPG, tb, 0, stream>>>(edges + E, E, N, deg);
    scan1_kernel<<<nbS, tb, 0, stream>>>(deg, rowptr, bsum, N);
    scan2_kernel<<<1, tb, 0, stream>>>(bsum, nbS);
    scan3_kernel<<<nbS, tb, 0, stream>>>(rowptr, bsum, cursor, N);
    scatter_part_kernel<<<NGROUPS * BPG, tb, 0, stream>>>(edges, E, N, cursor, csr_src);

    // layer 1 (f32 embeds in, bf16 x1 out with relu)
    gemm_mfma_kernel<true><<<nbM, tb, 0, stream>>>(embeds, W1, as1, ad1,
                                                   hb, hs, hd, N);
    gather_kernel<true><<<nbN, tb, 0, stream>>>((const unsigned int*)hb, hs, hd,
                                                rowptr, deg, csr_src, b1, x1b, N);
    // layer 2 (bf16 x1 in, f32 out)
    gemm_mfma_kernel<false><<<nbM, tb, 0, stream>>>(x1b, W2, as2, ad2,
                                                    hb, hs, hd, N);
    gather_kernel<false><<<nbN, tb, 0, stream>>>((const unsigned int*)hb, hs, hd,
                                                 rowptr, deg, csr_src, b2, d_out, N);
}

// Round 7
// 176.645 us; speedup vs baseline: 2.6549x; 1.0166x over previous
//
#include <hip/hip_runtime.h>

#define D 64
#define NGROUPS 8
#define BPG 128          // blocks per dst-range group

typedef __attribute__((ext_vector_type(8))) __bf16 bf16x8;
typedef __attribute__((ext_vector_type(4))) float f32x4;

__device__ __forceinline__ unsigned short f2b(float f) {   // f32 -> bf16 RNE
    unsigned int u = __float_as_uint(f);
    return (unsigned short)((u + 0x7fffu + ((u >> 16) & 1u)) >> 16);
}

// ---------------- zero deg ----------------

__global__ __launch_bounds__(256) void zero_kernel(int* __restrict__ p, int n) {
    int idx = blockIdx.x * 256 + threadIdx.x;
    if (idx < n) p[idx] = 0;
}

// ---------------- CSR build (dst-range partitioned, XCD-local writes) -------

__global__ __launch_bounds__(256) void hist_part_kernel(
    const int* __restrict__ dst, int E, int N, int* __restrict__ deg)
{
    int g  = blockIdx.x & (NGROUPS - 1);
    int bg = blockIdx.x >> 3;
    int lo = (int)((long long)g * N / NGROUPS);
    int hi = (int)((long long)(g + 1) * N / NGROUPS);
    int total = E + N;
    for (int e = bg * 256 + threadIdx.x; e < total; e += BPG * 256) {
        int d = (e < E) ? dst[e] : (e - E);
        if (d >= lo && d < hi) atomicAdd(&deg[d], 1);
    }
}

__global__ void scan1_kernel(const int* __restrict__ deg, int* __restrict__ rowptr,
                             int* __restrict__ bsum, int N) {
    __shared__ int tmp[256];
    int t = threadIdx.x;
    int idx = blockIdx.x * 256 + t;
    int v = (idx < N) ? deg[idx] : 0;
    tmp[t] = v;
    __syncthreads();
    for (int off = 1; off < 256; off <<= 1) {
        int add = (t >= off) ? tmp[t - off] : 0;
        __syncthreads();
        tmp[t] += add;
        __syncthreads();
    }
    if (idx < N) rowptr[idx] = tmp[t] - v;
    if (t == 255) bsum[blockIdx.x] = tmp[255];
}

__global__ void scan2_kernel(int* __restrict__ bsum, int nb) {
    __shared__ int tmp[256];
    int t = threadIdx.x;
    int v = (t < nb) ? bsum[t] : 0;
    tmp[t] = v;
    __syncthreads();
    for (int off = 1; off < 256; off <<= 1) {
        int add = (t >= off) ? tmp[t - off] : 0;
        __syncthreads();
        tmp[t] += add;
        __syncthreads();
    }
    if (t < nb) bsum[t] = tmp[t] - v;
}

__global__ void scan3_kernel(int* __restrict__ rowptr, const int* __restrict__ bsum,
                             int* __restrict__ cursor, int N) {
    int idx = blockIdx.x * 256 + threadIdx.x;
    if (idx >= N) return;
    int v = rowptr[idx] + bsum[blockIdx.x];
    rowptr[idx] = v;
    cursor[idx] = v;
}

__global__ __launch_bounds__(256) void scatter_part_kernel(
    const int* __restrict__ edges, int E, int N,
    int* __restrict__ cursor, int* __restrict__ csr_src)
{
    int g  = blockIdx.x & (NGROUPS - 1);
    int bg = blockIdx.x >> 3;
    int lo = (int)((long long)g * N / NGROUPS);
    int hi = (int)((long long)(g + 1) * N / NGROUPS);
    int total = E + N;
    for (int e = bg * 256 + threadIdx.x; e < total; e += BPG * 256) {
        int d = (e < E) ? edges[E + e] : (e - E);
        if (d >= lo && d < hi) {
            int s = (e < E) ? edges[e] : d;
            int pos = atomicAdd(&cursor[d], 1);
            csr_src[pos] = s;
        }
    }
}

// ---------------- h = x @ W via MFMA (bf16), + attention scalars ------------
// Wave computes 16 rows x 64 cols: 8x mfma_f32_16x16x32_bf16.  [m89 layouts]

template <bool SRC_F32>
__global__ __launch_bounds__(256) void gemm_mfma_kernel(
    const void* __restrict__ xin, const float* __restrict__ W,
    const float* __restrict__ a_src, const float* __restrict__ a_dst,
    unsigned short* __restrict__ hb,     // [N][64] bf16 out
    float* __restrict__ hs, float* __restrict__ hd, int N)
{
    int t = threadIdx.x;
    int wave = t >> 6;
    int lane = t & 63;
    int lr = lane & 15;
    int lg = lane >> 4;

    int row0 = blockIdx.x * 64 + wave * 16;

    bf16x8 bfr[4][2];
    #pragma unroll
    for (int c = 0; c < 4; ++c)
        #pragma unroll
        for (int kk = 0; kk < 2; ++kk) {
            union { unsigned short u[8]; bf16x8 v; } tmp;
            #pragma unroll
            for (int e = 0; e < 8; ++e)
                tmp.u[e] = f2b(W[(kk * 32 + lg * 8 + e) * 64 + c * 16 + lr]);
            bfr[c][kk] = tmp.v;
        }

    int arow = row0 + lr; if (arow >= N) arow = N - 1;
    bf16x8 afr[2];
    if constexpr (SRC_F32) {
        const float* xf = (const float*)xin;
        #pragma unroll
        for (int kk = 0; kk < 2; ++kk) {
            const float4* pr = (const float4*)(xf + (size_t)arow * D + kk * 32 + lg * 8);
            float4 v0 = pr[0], v1 = pr[1];
            union { unsigned short u[8]; bf16x8 v; } tmp;
            tmp.u[0] = f2b(v0.x); tmp.u[1] = f2b(v0.y);
            tmp.u[2] = f2b(v0.z); tmp.u[3] = f2b(v0.w);
            tmp.u[4] = f2b(v1.x); tmp.u[5] = f2b(v1.y);
            tmp.u[6] = f2b(v1.z); tmp.u[7] = f2b(v1.w);
            afr[kk] = tmp.v;
        }
    } else {
        const unsigned short* xb = (const unsigned short*)xin;
        #pragma unroll
        for (int kk = 0; kk < 2; ++kk) {
            union { uint4 r; bf16x8 v; } tmp;
            tmp.r = *(const uint4*)(xb + (size_t)arow * D + kk * 32 + lg * 8);
            afr[kk] = tmp.v;
        }
    }

    f32x4 acc[4];
    #pragma unroll
    for (int c = 0; c < 4; ++c) acc[c] = (f32x4){0.f, 0.f, 0.f, 0.f};

    #pragma unroll
    for (int kk = 0; kk < 2; ++kk)
        #pragma unroll
        for (int c = 0; c < 4; ++c)
            acc[c] = __builtin_amdgcn_mfma_f32_16x16x32_bf16(afr[kk], bfr[c][kk],
                                                             acc[c], 0, 0, 0);

    float asv[4], adv[4];
    #pragma unroll
    for (int c = 0; c < 4; ++c) {
        asv[c] = a_src[c * 16 + lr];
        adv[c] = a_dst[c * 16 + lr];
    }

    #pragma unroll
    for (int r = 0; r < 4; ++r) {
        int row = row0 + lg * 4 + r;
        float vs = 0.f, vd = 0.f;
        #pragma unroll
        for (int c = 0; c < 4; ++c) {
            float hv = acc[c][r];
            if (row < N) hb[(size_t)row * D + c * 16 + lr] = f2b(hv);
            vs = fmaf(hv, asv[c], vs);
            vd = fmaf(hv, adv[c], vd);
        }
        #pragma unroll
        for (int off = 8; off; off >>= 1) {
            vs += __shfl_xor(vs, off);
            vd += __shfl_xor(vd, off);
        }
        if (lr == 0 && row < N) { hs[row] = vs; hd[row] = vd; }
    }
}

// ---------------- segment softmax + aggregation (one wave per dst node) -----
// Logits: lane-parallel over 64 edges/chunk.  Aggregation: lane=(g,f); group
// g (16 lanes) handles edges e==g mod 4, lane covers feature quad 4f..4f+3
// (uint2 of bf16).  Per 4 edges: 2 ds_bpermute broadcasts + 1 dwordx2 load.

template <bool RELU>
__global__ __launch_bounds__(256) void gather_kernel(
    const unsigned short* __restrict__ hb,   // [N][64] bf16
    const float* __restrict__ hs, const float* __restrict__ hd,
    const int* __restrict__ rowptr, const int* __restrict__ deg,
    const int* __restrict__ csr_src,
    const float* __restrict__ bias, void* __restrict__ outv, int N)
{
    int t = threadIdx.x;
    int wave = t >> 6;
    int lane = t & 63;
    int i = blockIdx.x * 4 + wave;
    if (i >= N) return;

    int g = lane >> 4;        // edge subgroup 0..3
    int f = lane & 15;        // feature quad index

    int start = rowptr[i];
    int cnt = deg[i];
    float hdv = hd[i];

    float m = -1e30f, s = 0.f;
    float o0 = 0.f, o1 = 0.f, o2 = 0.f, o3 = 0.f;

    for (int base = 0; base < cnt; base += 64) {
        int rem = cnt - base; if (rem > 64) rem = 64;

        int myj = 0; float myl = -1e30f;
        if (lane < rem) {
            myj = csr_src[start + base + lane];
            float l = hs[myj] + hdv;
            myl = (l > 0.f) ? l : 0.2f * l;
        }

        float cm = myl;
        #pragma unroll
        for (int off = 32; off; off >>= 1) cm = fmaxf(cm, __shfl_xor(cm, off));
        if (cm > m) {                       // wave-uniform rescale (exact)
            float sc = __expf(m - cm);
            s *= sc; o0 *= sc; o1 *= sc; o2 *= sc; o3 *= sc;
            m = cm;
        }

        float p = __expf(myl - m);          // lanes >= rem: exp(-1e30) == 0
        float cs = p;
        #pragma unroll
        for (int off = 32; off; off >>= 1) cs += __shfl_xor(cs, off);
        s += cs;

        int iters = (rem + 3) >> 2;
        #pragma unroll 2
        for (int it = 0; it < iters; ++it) {
            int e = it * 4 + g;             // e>=rem: p==0, j==0 -> harmless
            int j = __shfl(myj, e);
            float pp = __shfl(p, e);
            uint2 hv = *(const uint2*)(hb + (size_t)j * 64 + f * 4);
            o0 = fmaf(pp, __uint_as_float(hv.x << 16), o0);
            o1 = fmaf(pp, __uint_as_float(hv.x & 0xffff0000u), o1);
            o2 = fmaf(pp, __uint_as_float(hv.y << 16), o2);
            o3 = fmaf(pp, __uint_as_float(hv.y & 0xffff0000u), o3);
        }
    }

    // sum partial o across the 4 edge subgroups
    #pragma unroll
    for (int off = 16; off <= 32; off <<= 1) {
        o0 += __shfl_xor(o0, off);
        o1 += __shfl_xor(o1, off);
        o2 += __shfl_xor(o2, off);
        o3 += __shfl_xor(o3, off);
    }

    if (g == 0) {
        float4 bv = ((const float4*)bias)[f];
        float inv = 1.f / s;
        float r0 = fmaf(o0, inv, bv.x);
        float r1 = fmaf(o1, inv, bv.y);
        float r2 = fmaf(o2, inv, bv.z);
        float r3 = fmaf(o3, inv, bv.w);
        if (RELU) {
            r0 = fmaxf(r0, 0.f); r1 = fmaxf(r1, 0.f);
            r2 = fmaxf(r2, 0.f); r3 = fmaxf(r3, 0.f);
            uint2 pk;
            pk.x = ((unsigned int)f2b(r1) << 16) | f2b(r0);
            pk.y = ((unsigned int)f2b(r3) << 16) | f2b(r2);
            ((uint2*)outv)[(size_t)i * 16 + f] = pk;
        } else {
            float4 r;
            r.x = r0; r.y = r1; r.z = r2; r.w = r3;
            ((float4*)outv)[(size_t)i * 16 + f] = r;
        }
    }
}

// ---------------- launch ----------------

extern "C" void kernel_launch(void* const* d_in, const int* in_sizes, int n_in,
                              void* d_out, int out_size, void* d_ws, size_t ws_size,
                              hipStream_t stream)
{
    const float* embeds = (const float*)d_in[0];
    const int*   edges  = (const int*)d_in[1];   // [2, E] row-major
    const float* W1  = (const float*)d_in[2];
    const float* as1 = (const float*)d_in[3];
    const float* ad1 = (const float*)d_in[4];
    const float* b1  = (const float*)d_in[5];
    const float* W2  = (const float*)d_in[6];
    const float* as2 = (const float*)d_in[7];
    const float* ad2 = (const float*)d_in[8];
    const float* b2  = (const float*)d_in[9];

    int N = in_sizes[0] / D;
    int E = in_sizes[1] / 2;
    int total = E + N;

    char* ws = (char*)d_ws;
    unsigned short* hb  = (unsigned short*)ws;  ws += (size_t)N * D * 2;
    unsigned short* x1b = (unsigned short*)ws;  ws += (size_t)N * D * 2;
    float* hs  = (float*)ws;  ws += (size_t)N * 4;
    float* hd  = (float*)ws;  ws += (size_t)N * 4;
    int* deg     = (int*)ws;  ws += (size_t)N * 4;
    int* rowptr  = (int*)ws;  ws += (size_t)N * 4;
    int* cursor  = (int*)ws;  ws += (size_t)N * 4;
    int* bsum    = (int*)ws;  ws += 1024 * 4;
    int* csr_src = (int*)ws;  ws += (size_t)total * 4;

    const int tb = 256;
    int nbS = (N + tb - 1) / tb;
    int nbN = (N + 3) / 4;
    int nbM = (N + 63) / 64;

    zero_kernel<<<nbS, tb, 0, stream>>>(deg, N);
    hist_part_kernel<<<NGROUPS * BPG, tb, 0, stream>>>(edges + E, E, N, deg);
    scan1_kernel<<<nbS, tb, 0, stream>>>(deg, rowptr, bsum, N);
    scan2_kernel<<<1, tb, 0, stream>>>(bsum, nbS);
    scan3_kernel<<<nbS, tb, 0, stream>>>(rowptr, bsum, cursor, N);
    scatter_part_kernel<<<NGROUPS * BPG, tb, 0, stream>>>(edges, E, N, cursor, csr_src);

    // layer 1 (f32 embeds in, bf16 x1 out with relu)
    gemm_mfma_kernel<true><<<nbM, tb, 0, stream>>>(embeds, W1, as1, ad1,
                                                   hb, hs, hd, N);
    gather_kernel<true><<<nbN, tb, 0, stream>>>(hb, hs, hd,
                                                rowptr, deg, csr_src, b1, x1b, N);
    // layer 2 (bf16 x1 in, f32 out)
    gemm_mfma_kernel<false><<<nbM, tb, 0, stream>>>(x1b, W2, as2, ad2,
                                                    hb, hs, hd, N);
    gather_kernel<false><<<nbN, tb, 0, stream>>>(hb, hs, hd,
                                                 rowptr, deg, csr_src, b2, d_out, N);
}